// Round 2
// baseline (268987.305 us; speedup 1.0000x reference)
//
#include <hip/hip_runtime.h>

// ============================================================================
// RNN-T greedy decode, MI355X. Single persistent cooperative kernel
// (256 blocks = 256 CUs, 1 block/CU forced by 151KB LDS), custom grid
// barrier, THREE barriers per symbol step:
//   P1: LSTM z = x@Wx + h@Wh + b   (Wx/Wh register-resident, 33.5MB total)
//   P2: q = tanh(E[t] + h2@W_pred + bj)  (W_pred register-resident)
//   P3: bf16 MFMA screen of logits from LDS-resident W_out fragments,
//       block-LOCAL certified threshold -> exact fp32 rescore from WoutT
//       -> argmax via device atomicMax (packed key: logit | 16384-v).
// Correctness of local threshold: the true argmax column c* satisfies
// L(c*) >= max_j L(j) >= max_{j in its block}(Lscreen_j - bnd_j), so c*
// always passes its own block's test and is rescored exactly.
// ============================================================================

typedef __attribute__((ext_vector_type(4))) float f32x4;
typedef __attribute__((ext_vector_type(8))) short bf16x8;

#define NBLK 256
#define NTHR 512
#define HD 1024
#define NVOC 16385
#define VBLANK 16384
#define TMAX 200

// LDS layout (bytes)
#define LDS_WFRAG 0        // 4 tiles * 32 kc * 64 lanes * 16B = 131072
#define LDS_QT    131072   // q~ bf16 [8][1024] swizzled = 16384
#define LDS_Z16   147456   // 16B zero block for A-frag pad rows
#define LDS_LBUF  147472   // screen logits [8][64] f32 = 2048
#define LDS_BND   149520   // per-column certified bound [64] f32 = 256
#define LDS_UN    149776   // union scratch 4608 (P1 reduce / P3 cand list)
#define LDS_TOTAL 154384

__device__ __forceinline__ unsigned short f2bf_rne(float f) {
  unsigned u = __float_as_uint(f);
  return (unsigned short)((u + 0x7FFFu + ((u >> 16) & 1u)) >> 16);
}
__device__ __forceinline__ unsigned mono32(float f) {
  unsigned u = __float_as_uint(f);
  return u ^ ((u >> 31) ? 0xFFFFFFFFu : 0x80000000u);
}

__device__ __forceinline__ void gridbar(unsigned* cnt, unsigned* gen) {
  __syncthreads();
  if (threadIdx.x == 0) {
    __threadfence();
    unsigned g = __hip_atomic_load(gen, __ATOMIC_RELAXED, __HIP_MEMORY_SCOPE_AGENT);
    unsigned old = __hip_atomic_fetch_add(cnt, 1u, __ATOMIC_ACQ_REL, __HIP_MEMORY_SCOPE_AGENT);
    if (old == NBLK - 1) {
      __hip_atomic_store(cnt, 0u, __ATOMIC_RELAXED, __HIP_MEMORY_SCOPE_AGENT);
      __hip_atomic_store(gen, g + 1u, __ATOMIC_RELEASE, __HIP_MEMORY_SCOPE_AGENT);
    } else {
      unsigned cur;
      do {
        __builtin_amdgcn_s_sleep(2);
        cur = __hip_atomic_load(gen, __ATOMIC_ACQUIRE, __HIP_MEMORY_SCOPE_AGENT);
      } while (cur == g);
    }
    __threadfence();
  }
  __syncthreads();
}

// ---------------- generic tiled transpose: in[R][C] -> out[C][R] ------------
__global__ void trk(const float* __restrict__ in, float* __restrict__ out,
                    int R, int C) {
  __shared__ float tl[32][33];
  const int bx = blockIdx.x * 32, by = blockIdx.y * 32;
  const size_t zoff = (size_t)blockIdx.z * R * C;
  const int tx = threadIdx.x, ty = threadIdx.y;
#pragma unroll
  for (int j = 0; j < 32; j += 8) {
    int r = by + ty + j, c = bx + tx;
    if (r < R && c < C) tl[ty + j][tx] = in[zoff + (size_t)r * C + c];
  }
  __syncthreads();
#pragma unroll
  for (int j = 0; j < 32; j += 8) {
    int orow = bx + ty + j, oc = by + tx;
    if (orow < C && oc < R) out[zoff + (size_t)orow * R + oc] = tl[tx][ty + j];
  }
}

// --------------- E[t][r][i] = sum_d encT[r][t][d] * Wenc[d][i] --------------
__global__ __launch_bounds__(512) void egemm_kernel(
    const float* __restrict__ encT, const float* __restrict__ Wenc,
    float* __restrict__ E) {
  const int il = blockIdx.y * 256 + (threadIdx.x & 255);
  const int rg = threadIdx.x >> 8;
  const int t0 = blockIdx.x * 4;
  float acc[16];
#pragma unroll
  for (int q = 0; q < 16; ++q) acc[q] = 0.f;
  for (int d = 0; d < 1024; ++d) {
    const float wv = Wenc[(size_t)d * 1024 + il];
#pragma unroll
    for (int q = 0; q < 16; ++q) {
      const int row = rg * 16 + q;
      const int tt = t0 + (row >> 3), rr2 = row & 7;
      acc[q] += wv * encT[((size_t)rr2 * TMAX + tt) * 1024 + d];
    }
  }
#pragma unroll
  for (int q = 0; q < 16; ++q) {
    const int row = rg * 16 + q;
    const int tt = t0 + (row >> 3), rr2 = row & 7;
    E[((size_t)tt * 8 + rr2) * 1024 + il] = acc[q];
  }
}

// ------------------------------ main decoder --------------------------------
__global__ __launch_bounds__(NTHR, 2) void decode_kernel(
    const int* __restrict__ lens_g, const float* __restrict__ emb,
    const float* __restrict__ bias4, const float* __restrict__ bj,
    const float* __restrict__ bout, const float* __restrict__ WxT,
    const float* __restrict__ WhT, const float* __restrict__ WpT,
    const float* __restrict__ WoutT, const float* __restrict__ E,
    float* __restrict__ qg, float* __restrict__ hA, float* __restrict__ hB0,
    float* __restrict__ hB1, unsigned long long* __restrict__ Res,
    unsigned* __restrict__ barc, unsigned* __restrict__ barg,
    float* __restrict__ out) {
  extern __shared__ char smem[];
  const int tid = threadIdx.x, bid = blockIdx.x;
  const int lane = tid & 63, w = tid >> 6;
  const int jg = tid & 15, kq = tid >> 4;       // P1 roles
  const int part = kq & 1, slice = kq >> 1;     // part 0 = x (Wx), 1 = h (Wh)
  const int k0 = slice * 64;
  const int colg = 4 * bid + (jg & 3) + 1024 * (jg >> 2);
  const int io = tid & 3, ks = tid >> 2;        // P2 roles

  int len[8], last[8];
#pragma unroll
  for (int r = 0; r < 8; ++r) {
    len[r] = lens_g[r];
    last[r] = VBLANK;
  }
  int Tloop = 1;
#pragma unroll
  for (int r = 0; r < 8; ++r) {
    int lr = len[r] < TMAX ? len[r] : TMAX;
    Tloop = Tloop > lr ? Tloop : lr;
  }
  const int S = 4 * Tloop;

  // ---- register-resident weights ----
  float wreg[64];
  {
    const float* wsrc = (part == 0 ? WxT : WhT) + (size_t)colg * HD + k0;
#pragma unroll
    for (int e = 0; e < 64; e += 4) *(f32x4*)&wreg[e] = *(const f32x4*)(wsrc + e);
  }
  float wp[8];
  {
    const float* wps = WpT + (size_t)(4 * bid + io) * HD + ks * 8;
    *(f32x4*)&wp[0] = *(const f32x4*)(wps);
    *(f32x4*)&wp[4] = *(const f32x4*)(wps + 4);
  }
  float boreg = 0.f;
  if (w < 4) boreg = bout[bid * 64 + w * 16 + (lane & 15)];

  // ---- build W_out bf16 fragments in LDS + certified error bounds ----
  {
    const int vl = tid & 63, kc8 = tid >> 6;
    const int vglob = bid * 64 + vl;
    const int tile = vl >> 4, col = vl & 15;
    float dsum = 0.f, ssum = 0.f;
    for (int k4 = kc8 * 128; k4 < kc8 * 128 + 128; k4 += 4) {
      f32x4 wv4 = *(const f32x4*)(WoutT + (size_t)vglob * 1024 + k4);
#pragma unroll
      for (int e4 = 0; e4 < 4; ++e4) {
        float wv = wv4[e4];
        int k = k4 + e4;
        unsigned short bw = f2bf_rne(wv);
        float wq = __uint_as_float((unsigned)bw << 16);
        dsum += fabsf(wv - wq);
        ssum += fabsf(wq);
        int kc = k >> 5, kg = (k >> 3) & 3, e = k & 7;
        *(unsigned short*)(smem + LDS_WFRAG + tile * 32768 + kc * 1024 +
                           (kg * 16 + col) * 16 + e * 2) = bw;
      }
    }
    float* dscr = (float*)(smem + LDS_UN);
    dscr[(vl * 8 + kc8) * 2 + 0] = dsum;
    dscr[(vl * 8 + kc8) * 2 + 1] = ssum;
    __syncthreads();
    if (tid < 64) {
      float ds = 0.f, ss = 0.f;
#pragma unroll
      for (int j2 = 0; j2 < 8; ++j2) {
        ds += dscr[(tid * 8 + j2) * 2];
        ss += dscr[(tid * 8 + j2) * 2 + 1];
      }
      // |L_exact - L_screen| <= dsum*max|q| + 2^-8*ssum + fp32-accum cushion
      ((float*)(smem + LDS_BND))[tid] = ds + 0.0039f * ss + 0.01f;
    }
    if (tid == NTHR - 1) {
      f32x4 z4 = {0.f, 0.f, 0.f, 0.f};
      *(f32x4*)(smem + LDS_Z16) = z4;
    }
    __syncthreads();
  }

  float cst = 0.f, c2l = 0.f, h2l = 0.f;  // c-state (threads tid<32 only)
  unsigned actmask = 0;

  for (int s = 0; s < S; ++s) {
    const int t = s >> 2, u = s & 3;
    unsigned adv = 0;
    // ---- consume previous step's argmax, update control ----
    if (s > 0) {
      int sym[8];
#pragma unroll
      for (int r = 0; r < 8; ++r)
        sym[r] = VBLANK - (int)(unsigned)(Res[r] & 0xFFFFFFFFull);
      if (bid == 0 && tid < 8) {
        const int tp = (s - 1) >> 2, up = (s - 1) & 3;
        int lab = ((actmask >> tid) & 1) ? sym[tid] : VBLANK;
        out[((size_t)tid * TMAX + tp) * 4 + up] = (float)lab;
      }
      unsigned na = 0;
#pragma unroll
      for (int r = 0; r < 8; ++r) {
        bool a = (actmask >> r) & 1;
        bool nb = (sym[r] != VBLANK);
        if (a && nb) {
          adv |= 1u << r;
          last[r] = sym[r];
          na |= 1u << r;
        }
      }
      actmask = na;
    }
    if (u == 0) {
      actmask = 0;
#pragma unroll
      for (int r = 0; r < 8; ++r)
        if (t < len[r]) actmask |= 1u << r;
    }
    const float* hBp = (s & 1) ? hB0 : hB1;
    float* hBc = (s & 1) ? hB1 : hB0;

    // ================= P1: LSTM =================
    float acc[8];
#pragma unroll
    for (int r = 0; r < 8; ++r) acc[r] = 0.f;
    if (part == 0) {
      if (s > 0) {
#pragma unroll
        for (int r = 0; r < 8; ++r) {
          const float* xs = emb + (size_t)last[r] * HD + k0;
#pragma unroll
          for (int e = 0; e < 64; e += 4) {
            f32x4 a = *(const f32x4*)(xs + e);
            acc[r] = fmaf(wreg[e], a[0],
                     fmaf(wreg[e + 1], a[1],
                     fmaf(wreg[e + 2], a[2], fmaf(wreg[e + 3], a[3], acc[r]))));
          }
        }
      }
    } else {
#pragma unroll
      for (int r = 0; r < 8; ++r) {
        const bool ad = (adv >> r) & 1;
        const float* hbp = hBp + r * HD + k0;
        float* hap = hA + r * HD + k0;
#pragma unroll
        for (int e = 0; e < 64; e += 4) {
          f32x4 hb = *(const f32x4*)(hbp + e);
          f32x4 ha = *(const f32x4*)(hap + e);
          f32x4 hv;
          hv[0] = ad ? hb[0] : ha[0];
          hv[1] = ad ? hb[1] : ha[1];
          hv[2] = ad ? hb[2] : ha[2];
          hv[3] = ad ? hb[3] : ha[3];
          acc[r] = fmaf(wreg[e], hv[0],
                   fmaf(wreg[e + 1], hv[1],
                   fmaf(wreg[e + 2], hv[2], fmaf(wreg[e + 3], hv[3], acc[r]))));
          if (jg == 0) *(f32x4*)(hap + e) = hv;  // idempotent in-place commit
        }
      }
    }
    // reduce: intra-wave over 4 kq-chunks, then cross-wave via LDS
    {
      float* wscr = (float*)(smem + LDS_UN);
      float* zfin = (float*)(smem + LDS_UN + 4096);
#pragma unroll
      for (int r = 0; r < 8; ++r) {
        float v = acc[r];
        v += __shfl_xor(v, 16);
        v += __shfl_xor(v, 32);
        acc[r] = v;
      }
      if (lane < 16) {
#pragma unroll
        for (int r = 0; r < 8; ++r) wscr[(w * 16 + lane) * 8 + r] = acc[r];
      }
      __syncthreads();
      if (tid < 128) {
        const int r = tid & 7, jgg = tid >> 3;
        float z = bias4[4 * bid + (jgg & 3) + 1024 * (jgg >> 2)];
#pragma unroll
        for (int ww = 0; ww < 8; ++ww) z += wscr[(ww * 16 + jgg) * 8 + r];
        zfin[r * 16 + jgg] = z;
      }
      __syncthreads();
      if (tid < 32) {
        const int r = tid >> 2, j = tid & 3;
        if (s > 0 && ((adv >> r) & 1)) cst = c2l;  // commit c-state
        const float zi = zfin[r * 16 + j], zf = zfin[r * 16 + j + 4];
        const float zg = zfin[r * 16 + j + 8], zo = zfin[r * 16 + j + 12];
        const float si = 1.f / (1.f + expf(-zi));
        const float sf = 1.f / (1.f + expf(-zf));
        const float so = 1.f / (1.f + expf(-zo));
        c2l = sf * cst + si * tanhf(zg);
        h2l = so * tanhf(c2l);
        hBc[r * HD + 4 * bid + j] = h2l;
      }
    }
    gridbar(barc, barg);

    // ================= P2: q = tanh(E + h2@Wp + bj) =================
    if (bid == 0 && tid == 0) {
#pragma unroll
      for (int r = 0; r < 8; ++r) Res[r] = 0ull;
    }
    {
      float a2[8];
      const int hoff = ks * 8;
#pragma unroll
      for (int r = 0; r < 8; ++r) {
        f32x4 h0 = *(const f32x4*)(hBc + r * HD + hoff);
        f32x4 h1 = *(const f32x4*)(hBc + r * HD + hoff + 4);
        a2[r] = wp[0] * h0[0] + wp[1] * h0[1] + wp[2] * h0[2] + wp[3] * h0[3] +
                wp[4] * h1[0] + wp[5] * h1[1] + wp[6] * h1[2] + wp[7] * h1[3];
      }
#pragma unroll
      for (int r = 0; r < 8; ++r) {
        float v = a2[r];
        v += __shfl_xor(v, 4);
        v += __shfl_xor(v, 8);
        v += __shfl_xor(v, 16);
        v += __shfl_xor(v, 32);
        a2[r] = v;
      }
      float* w2 = (float*)(smem + LDS_UN);
      if (lane < 4) {
#pragma unroll
        for (int r = 0; r < 8; ++r) w2[(w * 4 + lane) * 8 + r] = a2[r];
      }
      __syncthreads();
      if (tid < 32) {
        const int r = tid >> 2, ioo = tid & 3, col = 4 * bid + ioo;
        float sum = bj[col];
#pragma unroll
        for (int ww = 0; ww < 8; ++ww) sum += w2[(ww * 4 + ioo) * 8 + r];
        qg[r * HD + col] = tanhf(E[((size_t)t * 8 + r) * 1024 + col] + sum);
      }
    }
    gridbar(barc, barg);

    // ========== P3: screen + local certified threshold + exact rescore ======
    {
      unsigned* cnt = (unsigned*)(smem + LDS_UN);
      unsigned* list = cnt + 1;
      if (tid == 0) *cnt = 0;
      // -- stage q~ (bf16, swizzled) into LDS --
      const int base = tid * 16;
      const int rr = base >> 10, kk0 = base & 1023;
      float qv[16];
      *(f32x4*)&qv[0] = *(const f32x4*)(qg + base);
      *(f32x4*)&qv[4] = *(const f32x4*)(qg + base + 4);
      *(f32x4*)&qv[8] = *(const f32x4*)(qg + base + 8);
      *(f32x4*)&qv[12] = *(const f32x4*)(qg + base + 12);
#pragma unroll
      for (int p = 0; p < 8; ++p) {
        unsigned wrd = (unsigned)f2bf_rne(qv[2 * p]) |
                       ((unsigned)f2bf_rne(qv[2 * p + 1]) << 16);
        int kb = (kk0 + 2 * p) * 2;
        *(unsigned*)(smem + LDS_QT + rr * 2048 + (kb ^ ((rr & 7) << 4))) = wrd;
      }
      __syncthreads();
      float* Lb = (float*)(smem + LDS_LBUF);
      if (w < 4) {
        // -- MFMA screen: 16x16x32 bf16, A = q~ rows (8 real + 8 zero) --
        const int tile = w, col = lane & 15, kg = lane >> 4;
        f32x4 acc4 = {boreg, boreg, boreg, boreg};
#pragma unroll 8
        for (int kc = 0; kc < 32; ++kc) {
          bf16x8 av;
          if (col < 8) {
            int kb = kc * 64 + kg * 16;
            av = *(const bf16x8*)(smem + LDS_QT + col * 2048 +
                                  (kb ^ ((col & 7) << 4)));
          } else {
            av = *(const bf16x8*)(smem + LDS_Z16);
          }
          bf16x8 bv = *(const bf16x8*)(smem + LDS_WFRAG + tile * 32768 +
                                       kc * 1024 + lane * 16);
          acc4 = __builtin_amdgcn_mfma_f32_16x16x32_bf16(av, bv, acc4, 0, 0, 0);
        }
        if (lane < 32) {
          const int r0 = (lane >> 4) * 4;
#pragma unroll
          for (int e = 0; e < 4; ++e)
            Lb[(r0 + e) * 64 + tile * 16 + col] = acc4[e];
        }
      } else if (w == 4 && bid == 0) {
        // -- exact blank logit (seeds Res; payload 0 => v = VBLANK) --
        const int kb0 = lane * 16;
#pragma unroll
        for (int r = 0; r < 8; ++r) {
          float sum = 0.f;
#pragma unroll
          for (int e = 0; e < 16; e += 4) {
            f32x4 wv = *(const f32x4*)(WoutT + (size_t)VBLANK * HD + kb0 + e);
            f32x4 q2 = *(const f32x4*)(qg + r * HD + kb0 + e);
            sum += wv[0] * q2[0] + wv[1] * q2[1] + wv[2] * q2[2] + wv[3] * q2[3];
          }
          sum += __shfl_xor(sum, 1);
          sum += __shfl_xor(sum, 2);
          sum += __shfl_xor(sum, 4);
          sum += __shfl_xor(sum, 8);
          sum += __shfl_xor(sum, 16);
          sum += __shfl_xor(sum, 32);
          if (lane == 0) {
            float L = sum + bout[VBLANK];
            atomicMax(&Res[r], ((unsigned long long)mono32(L)) << 32);
          }
        }
      }
      __syncthreads();
      // -- block-local certified threshold, candidate list --
      {
        const float* bnd = (const float*)(smem + LDS_BND);
        const float Ld = Lb[w * 64 + lane];
        float m = Ld - bnd[lane];
        m = fmaxf(m, __shfl_xor(m, 1));
        m = fmaxf(m, __shfl_xor(m, 2));
        m = fmaxf(m, __shfl_xor(m, 4));
        m = fmaxf(m, __shfl_xor(m, 8));
        m = fmaxf(m, __shfl_xor(m, 16));
        m = fmaxf(m, __shfl_xor(m, 32));
        if (Ld + bnd[lane] >= m) {
          unsigned pos = atomicAdd(cnt, 1u);
          list[pos] = ((unsigned)w << 16) | (unsigned)(bid * 64 + lane);
        }
      }
      __syncthreads();
      // -- exact fp32 rescore of candidates from WoutT (coalesced) --
      const unsigned nc = *cnt;
      for (unsigned ci = (unsigned)w; ci < nc; ci += 8) {
        const unsigned ent = list[ci];
        const int rr2 = (int)(ent >> 16), v = (int)(ent & 0xFFFFu);
        const int kb0 = lane * 16;
        float sum = 0.f;
#pragma unroll
        for (int e = 0; e < 16; e += 4) {
          f32x4 q2 = *(const f32x4*)(qg + rr2 * HD + kb0 + e);
          f32x4 wv = *(const f32x4*)(WoutT + (size_t)v * HD + kb0 + e);
          sum += q2[0] * wv[0] + q2[1] * wv[1] + q2[2] * wv[2] + q2[3] * wv[3];
        }
        sum += __shfl_xor(sum, 1);
        sum += __shfl_xor(sum, 2);
        sum += __shfl_xor(sum, 4);
        sum += __shfl_xor(sum, 8);
        sum += __shfl_xor(sum, 16);
        sum += __shfl_xor(sum, 32);
        if (lane == 0) {
          float L = sum + bout[v];
          atomicMax(&Res[rr2], (((unsigned long long)mono32(L)) << 32) |
                                   (unsigned long long)(unsigned)(VBLANK - v));
        }
      }
    }
    gridbar(barc, barg);
  }  // s loop

  // ================= epilogue =================
  {
    int sym[8];
#pragma unroll
    for (int r = 0; r < 8; ++r)
      sym[r] = VBLANK - (int)(unsigned)(Res[r] & 0xFFFFFFFFull);
    if (bid == 0 && tid < 8) {
      int lab = ((actmask >> tid) & 1) ? sym[tid] : VBLANK;
      out[((size_t)tid * TMAX + (Tloop - 1)) * 4 + 3] = (float)lab;
    }
    unsigned advf = 0;
#pragma unroll
    for (int r = 0; r < 8; ++r)
      if (((actmask >> r) & 1) && sym[r] != VBLANK) advf |= 1u << r;
    if (tid < 32) {
      const int r = tid >> 2, j = tid & 3, col = 4 * bid + j;
      const bool ad = (advf >> r) & 1;
      out[6400 + (size_t)r * HD + col] = ad ? h2l : hA[r * HD + col];
      out[6400 + 8192 + (size_t)r * HD + col] = ad ? c2l : cst;
    }
    if (bid == 0 && Tloop < TMAX) {
      const int per = (TMAX - Tloop) * 4;
      const int ntail = 8 * per;
      for (int idx = tid; idx < ntail; idx += NTHR) {
        int r = idx / per, rem = idx % per;
        int tt = Tloop + (rem >> 2), uu = rem & 3;
        out[((size_t)r * TMAX + tt) * 4 + uu] = (float)VBLANK;
      }
    }
  }
}

// ============================================================================
extern "C" void kernel_launch(void* const* d_in, const int* in_sizes, int n_in,
                              void* d_out, int out_size, void* d_ws,
                              size_t ws_size, hipStream_t stream) {
  const float* enc = (const float*)d_in[0];   // (8,1024,200)
  const int* lens = (const int*)d_in[1];      // (8,)
  const float* emb = (const float*)d_in[2];   // (16385,1024)
  const float* Wx = (const float*)d_in[3];    // (1024,4096)
  const float* Wh = (const float*)d_in[4];    // (1024,4096)
  const float* b = (const float*)d_in[5];     // (4096,)
  const float* Wenc = (const float*)d_in[6];  // (1024,1024)
  const float* Wpred = (const float*)d_in[7]; // (1024,1024)
  const float* bj = (const float*)d_in[8];    // (1024,)
  const float* Wout = (const float*)d_in[9];  // (1024,16385)
  const float* bout = (const float*)d_in[10]; // (16385,)
  float* out = (float*)d_out;                 // labels(6400)|h(8192)|c(8192)

  float* ws = (float*)d_ws;                   // needs ~118 MB
  float* encT = ws;                           // 8*200*1024      = 1638400
  float* E = encT + 1638400;                  // 200*8*1024      = 1638400
  float* WxT = E + 1638400;                   // 4096*1024       = 4194304
  float* WhT = WxT + 4194304;                 // 4096*1024       = 4194304
  float* WpT = WhT + 4194304;                 // 1024*1024       = 1048576
  float* WoutT = WpT + 1048576;               // 16385*1024      = 16778240
  float* qg = WoutT + 16778240;               // 8192
  float* hA = qg + 8192;                      // 8192
  float* hB0 = hA + 8192;                     // 8192
  float* hB1 = hB0 + 8192;                    // 8192
  unsigned long long* Res = (unsigned long long*)(hB1 + 8192);  // 8 u64
  unsigned* barc = (unsigned*)(Res + 8);      // barrier counter
  unsigned* barg = barc + 1;                  // barrier generation

  hipFuncSetAttribute(reinterpret_cast<const void*>(decode_kernel),
                      hipFuncAttributeMaxDynamicSharedMemorySize, LDS_TOTAL);

  hipMemsetAsync(hA, 0, 8192 * sizeof(float), stream);  // h0 = 0
  hipMemsetAsync(Res, 0, 72, stream);                   // Res + barc + barg

  trk<<<dim3(128, 32, 1), dim3(32, 8), 0, stream>>>(Wx, WxT, 1024, 4096);
  trk<<<dim3(128, 32, 1), dim3(32, 8), 0, stream>>>(Wh, WhT, 1024, 4096);
  trk<<<dim3(32, 32, 1), dim3(32, 8), 0, stream>>>(Wpred, WpT, 1024, 1024);
  trk<<<dim3(7, 32, 8), dim3(32, 8), 0, stream>>>(enc, encT, 1024, 200);
  trk<<<dim3(513, 32, 1), dim3(32, 8), 0, stream>>>(Wout, WoutT, 1024, NVOC);
  egemm_kernel<<<dim3(50, 4), 512, 0, stream>>>(encT, Wenc, E);

  void* params[] = {(void*)&lens, (void*)&emb,  (void*)&b,    (void*)&bj,
                    (void*)&bout, (void*)&WxT,  (void*)&WhT,  (void*)&WpT,
                    (void*)&WoutT,(void*)&E,    (void*)&qg,   (void*)&hA,
                    (void*)&hB0,  (void*)&hB1,  (void*)&Res,  (void*)&barc,
                    (void*)&barg, (void*)&out};
  hipLaunchCooperativeKernel(reinterpret_cast<const void*>(decode_kernel),
                             dim3(NBLK), dim3(NTHR), params, LDS_TOTAL, stream);
}

// Round 4
// 70260.358 us; speedup vs baseline: 3.8284x; 3.8284x over previous
//
#include <hip/hip_runtime.h>

// ============================================================================
// RNN-T greedy decode, MI355X. Single persistent cooperative kernel
// (256 blocks = 256 CUs, 1 block/CU forced by 151KB LDS), epoch grid barrier,
// THREE barriers per symbol step.
// KEY (round 3/4): all cross-block state exchanged via RELAXED agent-scope
// atomics (global_load/store sc1 -> coherent at L3, NO L2 invalidation).
// No __threadfence / acquire / release anywhere in the hot loop -- round 2
// showed those emit buffer_inv/buffer_wbl2 per use, invalidating the whole
// XCD L2 (192 GB of traffic, 305 ms). Ordering is manual: s_waitcnt vmcnt(0)
// before barrier entry; L3 is the coherence point for sc1 accesses.
// Round 4: bounded barrier spin (fail-visible, not hang) -- if the sc1
// visibility model is wrong we terminate with garbage + counters instead of
// hanging the container.
// ============================================================================

typedef __attribute__((ext_vector_type(4))) float f32x4;
typedef __attribute__((ext_vector_type(4))) unsigned u32x4;
typedef __attribute__((ext_vector_type(8))) short bf16x8;

#define NBLK 256
#define NTHR 512
#define HD 1024
#define NVOC 16385
#define VBLANK 16384
#define TMAX 200

// LDS layout (bytes)
#define LDS_WFRAG 0        // 4 tiles * 32 kc * 64 lanes * 16B = 131072
#define LDS_QT    131072   // q~ bf16 [8][1024] swizzled = 16384
#define LDS_Z16   147456   // 16B zero block for A-frag pad rows
#define LDS_LBUF  147472   // screen logits [8][64] f32 = 2048
#define LDS_BND   149520   // per-column certified bound [64] f32 = 256
#define LDS_UN    149776   // union scratch 4608 (P1 reduce / P3 cand list)
#define LDS_SYM   154384   // sym broadcast [8] int = 32
#define LDS_FLAG  154416   // barrier-broken sticky flag (diagnostic) = 4
#define LDS_TOTAL 154432

#define AT_RLX __ATOMIC_RELAXED
#define SC_AGT __HIP_MEMORY_SCOPE_AGENT

__device__ __forceinline__ unsigned short f2bf_rne(float f) {
  unsigned u = __float_as_uint(f);
  return (unsigned short)((u + 0x7FFFu + ((u >> 16) & 1u)) >> 16);
}
__device__ __forceinline__ unsigned mono32(float f) {
  unsigned u = __float_as_uint(f);
  return u ^ ((u >> 31) ? 0xFFFFFFFFu : 0x80000000u);
}
// coherent (L3) 16B load as 2x relaxed 8B atomics
__device__ __forceinline__ f32x4 ald4(const float* p) {
  union { unsigned long long u; float f[2]; } a, b;
  a.u = __hip_atomic_load((const unsigned long long*)p, AT_RLX, SC_AGT);
  b.u = __hip_atomic_load((const unsigned long long*)(p + 2), AT_RLX, SC_AGT);
  f32x4 r;
  r[0] = a.f[0]; r[1] = a.f[1]; r[2] = b.f[0]; r[3] = b.f[1];
  return r;
}
__device__ __forceinline__ void ast(float* p, float v) {
  __hip_atomic_store(p, v, AT_RLX, SC_AGT);
}

// epoch barrier: monotone counter, relaxed atomics only, bounded spin.
// On timeout (sc1-visibility model wrong / lost block): set sticky flag,
// stop synchronizing -> kernel terminates fast with wrong results instead
// of hanging (fail-visible diagnostic).
__device__ __forceinline__ void gridbar(unsigned* cnt, unsigned* gen,
                                        unsigned epoch, unsigned* bflag) {
  asm volatile("s_waitcnt vmcnt(0) lgkmcnt(0)" ::: "memory");
  __syncthreads();
  if (threadIdx.x == 0 && *bflag == 0u) {
    unsigned old = __hip_atomic_fetch_add(cnt, 1u, AT_RLX, SC_AGT);
    if (old == epoch * NBLK - 1) {
      __hip_atomic_store(gen, epoch, AT_RLX, SC_AGT);
    } else {
      unsigned spins = 0;
      while (__hip_atomic_load(gen, AT_RLX, SC_AGT) < epoch) {
        __builtin_amdgcn_s_sleep(2);
        if (++spins > 8000000u) { *bflag = 1u; break; }
      }
    }
  }
  __syncthreads();
}

// ---------------- generic tiled transpose: in[R][C] -> out[C][R] ------------
__global__ void trk(const float* __restrict__ in, float* __restrict__ out,
                    int R, int C) {
  __shared__ float tl[32][33];
  const int bx = blockIdx.x * 32, by = blockIdx.y * 32;
  const size_t zoff = (size_t)blockIdx.z * R * C;
  const int tx = threadIdx.x, ty = threadIdx.y;
#pragma unroll
  for (int j = 0; j < 32; j += 8) {
    int r = by + ty + j, c = bx + tx;
    if (r < R && c < C) tl[ty + j][tx] = in[zoff + (size_t)r * C + c];
  }
  __syncthreads();
#pragma unroll
  for (int j = 0; j < 32; j += 8) {
    int orow = bx + ty + j, oc = by + tx;
    if (orow < C && oc < R) out[zoff + (size_t)orow * R + oc] = tl[tx][ty + j];
  }
}

// --------------- E[t][r][i] = sum_d encT[r][t][d] * Wenc[d][i] --------------
__global__ __launch_bounds__(512) void egemm_kernel(
    const float* __restrict__ encT, const float* __restrict__ Wenc,
    float* __restrict__ E) {
  const int il = blockIdx.y * 256 + (threadIdx.x & 255);
  const int rg = threadIdx.x >> 8;
  const int t0 = blockIdx.x * 4;
  float acc[16];
#pragma unroll
  for (int q = 0; q < 16; ++q) acc[q] = 0.f;
  for (int d = 0; d < 1024; ++d) {
    const float wv = Wenc[(size_t)d * 1024 + il];
#pragma unroll
    for (int q = 0; q < 16; ++q) {
      const int row = rg * 16 + q;
      const int tt = t0 + (row >> 3), rr2 = row & 7;
      acc[q] += wv * encT[((size_t)rr2 * TMAX + tt) * 1024 + d];
    }
  }
#pragma unroll
  for (int q = 0; q < 16; ++q) {
    const int row = rg * 16 + q;
    const int tt = t0 + (row >> 3), rr2 = row & 7;
    E[((size_t)tt * 8 + rr2) * 1024 + il] = acc[q];
  }
}

// ------------------------------ main decoder --------------------------------
__global__ __launch_bounds__(NTHR, 2) void decode_kernel(
    const int* __restrict__ lens_g, const float* __restrict__ emb,
    const float* __restrict__ bias4, const float* __restrict__ bj,
    const float* __restrict__ bout, const float* __restrict__ WxT,
    const float* __restrict__ WhT, const float* __restrict__ WpT,
    const float* __restrict__ WoutT, const float* __restrict__ E,
    float* __restrict__ qg, unsigned* __restrict__ qgb,
    float* __restrict__ hA, float* __restrict__ hB0, float* __restrict__ hB1,
    unsigned long long* __restrict__ Res, unsigned* __restrict__ barc,
    unsigned* __restrict__ barg, float* __restrict__ out) {
  extern __shared__ char smem[];
  const int tid = threadIdx.x, bid = blockIdx.x;
  const int lane = tid & 63, w = tid >> 6;
  const int jg = tid & 15, kq = tid >> 4;       // P1 roles
  const int part = kq & 1, slice = kq >> 1;     // part 0 = x (Wx), 1 = h (Wh)
  const int k0 = slice * 64;
  const int colg = 4 * bid + (jg & 3) + 1024 * (jg >> 2);
  const int io = tid & 3, ks = tid >> 2;        // P2 roles
  unsigned* bflag = (unsigned*)(smem + LDS_FLAG);

  int len[8], last[8];
#pragma unroll
  for (int r = 0; r < 8; ++r) {
    len[r] = lens_g[r];
    last[r] = VBLANK;
  }
  int Tloop = 1;
#pragma unroll
  for (int r = 0; r < 8; ++r) {
    int lr = len[r] < TMAX ? len[r] : TMAX;
    Tloop = Tloop > lr ? Tloop : lr;
  }
  const int S = 4 * Tloop;

  // ---- register-resident weights ----
  float wreg[64];
  {
    const float* wsrc = (part == 0 ? WxT : WhT) + (size_t)colg * HD + k0;
#pragma unroll
    for (int e = 0; e < 64; e += 4) *(f32x4*)&wreg[e] = *(const f32x4*)(wsrc + e);
  }
  float wp[8];
  {
    const float* wps = WpT + (size_t)(4 * bid + io) * HD + ks * 8;
    *(f32x4*)&wp[0] = *(const f32x4*)(wps);
    *(f32x4*)&wp[4] = *(const f32x4*)(wps + 4);
  }
  float boreg = 0.f;
  if (w < 4) boreg = bout[bid * 64 + w * 16 + (lane & 15)];

  // ---- build W_out bf16 fragments in LDS + certified error bounds ----
  {
    if (tid == 0) *bflag = 0u;
    const int vl = tid & 63, kc8 = tid >> 6;
    const int vglob = bid * 64 + vl;
    const int tile = vl >> 4, col = vl & 15;
    float dsum = 0.f, ssum = 0.f;
    for (int k4 = kc8 * 128; k4 < kc8 * 128 + 128; k4 += 4) {
      f32x4 wv4 = *(const f32x4*)(WoutT + (size_t)vglob * 1024 + k4);
#pragma unroll
      for (int e4 = 0; e4 < 4; ++e4) {
        float wv = wv4[e4];
        int k = k4 + e4;
        unsigned short bw = f2bf_rne(wv);
        float wq = __uint_as_float((unsigned)bw << 16);
        dsum += fabsf(wv - wq);
        ssum += fabsf(wq);
        int kc = k >> 5, kg = (k >> 3) & 3, e = k & 7;
        *(unsigned short*)(smem + LDS_WFRAG + tile * 32768 + kc * 1024 +
                           (kg * 16 + col) * 16 + e * 2) = bw;
      }
    }
    float* dscr = (float*)(smem + LDS_UN);
    dscr[(vl * 8 + kc8) * 2 + 0] = dsum;
    dscr[(vl * 8 + kc8) * 2 + 1] = ssum;
    __syncthreads();
    if (tid < 64) {
      float ds = 0.f, ss = 0.f;
#pragma unroll
      for (int j2 = 0; j2 < 8; ++j2) {
        ds += dscr[(tid * 8 + j2) * 2];
        ss += dscr[(tid * 8 + j2) * 2 + 1];
      }
      ((float*)(smem + LDS_BND))[tid] = ds + 0.0039f * ss + 0.01f;
    }
    if (tid == NTHR - 1) {
      f32x4 z4 = {0.f, 0.f, 0.f, 0.f};
      *(f32x4*)(smem + LDS_Z16) = z4;
    }
    __syncthreads();
  }

  float cst = 0.f, c2l = 0.f, h2l = 0.f;  // c-state (threads tid<32 only)
  unsigned actmask = 0;
  unsigned bep = 0;  // barrier epoch

  for (int s = 0; s < S; ++s) {
    const int t = s >> 2, u = s & 3;
    unsigned adv = 0;
    // ---- consume previous step's argmax (LDS broadcast), update control ----
    if (s > 0) {
      if (tid < 8) {
        unsigned long long rv = __hip_atomic_load(&Res[tid], AT_RLX, SC_AGT);
        ((int*)(smem + LDS_SYM))[tid] =
            VBLANK - (int)(unsigned)(rv & 0xFFFFFFFFull);
      }
      __syncthreads();
      int sym[8];
#pragma unroll
      for (int r = 0; r < 8; ++r) sym[r] = ((const int*)(smem + LDS_SYM))[r];
      if (bid == 0 && tid < 8) {
        const int tp = (s - 1) >> 2, up = (s - 1) & 3;
        int lab = ((actmask >> tid) & 1) ? sym[tid] : VBLANK;
        out[((size_t)tid * TMAX + tp) * 4 + up] = (float)lab;
      }
      unsigned na = 0;
#pragma unroll
      for (int r = 0; r < 8; ++r) {
        bool a = (actmask >> r) & 1;
        bool nb = (sym[r] != VBLANK);
        if (a && nb) {
          adv |= 1u << r;
          last[r] = sym[r];
          na |= 1u << r;
        }
      }
      actmask = na;
      // owner-block commit of h2(s-1)/c2(s-1) for advanced rows.
      // Race-free: rows with adv=1 are exactly the rows no block reads
      // from hA this step (they read hBp instead).
      if (tid < 32) {
        const int r = tid >> 2, j = tid & 3;
        if ((adv >> r) & 1) {
          ast(&hA[r * HD + 4 * bid + j], h2l);
          cst = c2l;
        }
      }
    }
    if (u == 0) {
      actmask = 0;
#pragma unroll
      for (int r = 0; r < 8; ++r)
        if (t < len[r]) actmask |= 1u << r;
    }
    const float* hBp = (s & 1) ? hB0 : hB1;
    float* hBc = (s & 1) ? hB1 : hB0;

    // ================= P1: LSTM =================
    float acc[8];
#pragma unroll
    for (int r = 0; r < 8; ++r) acc[r] = 0.f;
    if (part == 0) {
      if (s > 0) {
#pragma unroll
        for (int r = 0; r < 8; ++r) {
          const float* xs = emb + (size_t)last[r] * HD + k0;  // cached: RO
#pragma unroll
          for (int e = 0; e < 64; e += 4) {
            f32x4 a = *(const f32x4*)(xs + e);
            acc[r] = fmaf(wreg[e], a[0],
                     fmaf(wreg[e + 1], a[1],
                     fmaf(wreg[e + 2], a[2], fmaf(wreg[e + 3], a[3], acc[r]))));
          }
        }
      }
    } else {
#pragma unroll
      for (int r = 0; r < 8; ++r) {
        const float* hs = (((adv >> r) & 1) ? hBp : hA) + r * HD + k0;
#pragma unroll
        for (int e = 0; e < 64; e += 4) {
          f32x4 hv = ald4(hs + e);
          acc[r] = fmaf(wreg[e], hv[0],
                   fmaf(wreg[e + 1], hv[1],
                   fmaf(wreg[e + 2], hv[2], fmaf(wreg[e + 3], hv[3], acc[r]))));
        }
      }
    }
    // reduce: intra-wave over 4 kq-chunks, then cross-wave via LDS
    {
      float* wscr = (float*)(smem + LDS_UN);
      float* zfin = (float*)(smem + LDS_UN + 4096);
#pragma unroll
      for (int r = 0; r < 8; ++r) {
        float v = acc[r];
        v += __shfl_xor(v, 16);
        v += __shfl_xor(v, 32);
        acc[r] = v;
      }
      if (lane < 16) {
#pragma unroll
        for (int r = 0; r < 8; ++r) wscr[(w * 16 + lane) * 8 + r] = acc[r];
      }
      __syncthreads();
      if (tid < 128) {
        const int r = tid & 7, jgg = tid >> 3;
        float z = bias4[4 * bid + (jgg & 3) + 1024 * (jgg >> 2)];
#pragma unroll
        for (int ww = 0; ww < 8; ++ww) z += wscr[(ww * 16 + jgg) * 8 + r];
        zfin[r * 16 + jgg] = z;
      }
      __syncthreads();
      if (tid < 32) {
        const int r = tid >> 2, j = tid & 3;
        const float zi = zfin[r * 16 + j], zf = zfin[r * 16 + j + 4];
        const float zg = zfin[r * 16 + j + 8], zo = zfin[r * 16 + j + 12];
        const float si = 1.f / (1.f + expf(-zi));
        const float sf = 1.f / (1.f + expf(-zf));
        const float so = 1.f / (1.f + expf(-zo));
        c2l = sf * cst + si * tanhf(zg);
        h2l = so * tanhf(c2l);
        ast(&hBc[r * HD + 4 * bid + j], h2l);
      }
    }
    gridbar(barc, barg, ++bep, bflag);

    // ================= P2: q = tanh(E + h2@Wp + bj) =================
    if (bid == 0 && tid < 8)
      __hip_atomic_store(&Res[tid], 0ull, AT_RLX, SC_AGT);
    {
      float a2[8];
      const int hoff = ks * 8;
#pragma unroll
      for (int r = 0; r < 8; ++r) {
        f32x4 h0 = ald4(hBc + r * HD + hoff);
        f32x4 h1 = ald4(hBc + r * HD + hoff + 4);
        a2[r] = wp[0] * h0[0] + wp[1] * h0[1] + wp[2] * h0[2] + wp[3] * h0[3] +
                wp[4] * h1[0] + wp[5] * h1[1] + wp[6] * h1[2] + wp[7] * h1[3];
      }
#pragma unroll
      for (int r = 0; r < 8; ++r) {
        float v = a2[r];
        v += __shfl_xor(v, 4);
        v += __shfl_xor(v, 8);
        v += __shfl_xor(v, 16);
        v += __shfl_xor(v, 32);
        a2[r] = v;
      }
      float* w2 = (float*)(smem + LDS_UN);
      if (lane < 4) {
#pragma unroll
        for (int r = 0; r < 8; ++r) w2[(w * 4 + lane) * 8 + r] = a2[r];
      }
      __syncthreads();
      if (tid < 32) {
        const int r = tid >> 2, ioo = tid & 3, col = 4 * bid + ioo;
        float sum = bj[col];
#pragma unroll
        for (int ww = 0; ww < 8; ++ww) sum += w2[(ww * 4 + ioo) * 8 + r];
        float qv = tanhf(E[((size_t)t * 8 + r) * 1024 + col] + sum);
        ast(&qg[r * HD + col], qv);
        float qo = __shfl_xor(qv, 1);  // partner col within pair
        if ((ioo & 1) == 0) {
          unsigned word =
              (unsigned)f2bf_rne(qv) | ((unsigned)f2bf_rne(qo) << 16);
          __hip_atomic_store(&qgb[r * 512 + 2 * bid + (ioo >> 1)], word,
                             AT_RLX, SC_AGT);
        }
      }
    }
    gridbar(barc, barg, ++bep, bflag);

    // ========== P3: screen + local certified threshold + exact rescore ======
    {
      unsigned* cnt = (unsigned*)(smem + LDS_UN);
      unsigned* list = cnt + 1;
      if (tid == 0) *cnt = 0;
      // -- stage q~ (bf16, pre-converted) into LDS, swizzled --
      const int rr = tid >> 6;
      const int c32 = (tid & 63) * 8;
      unsigned vv[8];
#pragma unroll
      for (int i = 0; i < 8; ++i)
        vv[i] = __hip_atomic_load(&qgb[rr * 512 + c32 + i], AT_RLX, SC_AGT);
      {
        const int sw = (rr & 7) << 4;
        char* qrow = smem + LDS_QT + rr * 2048;
        const int kb = (tid & 63) * 32;
        *(u32x4*)(qrow + (kb ^ sw)) = *(u32x4*)&vv[0];
        *(u32x4*)(qrow + ((kb + 16) ^ sw)) = *(u32x4*)&vv[4];
      }
      __syncthreads();
      float* Lb = (float*)(smem + LDS_LBUF);
      if (w < 4) {
        // -- MFMA screen: 16x16x32 bf16, A = q~ rows (8 real + 8 zero) --
        const int tile = w, col = lane & 15, kg = lane >> 4;
        f32x4 acc4 = {boreg, boreg, boreg, boreg};
#pragma unroll 8
        for (int kc = 0; kc < 32; ++kc) {
          bf16x8 av;
          if (col < 8) {
            int kb = kc * 64 + kg * 16;
            av = *(const bf16x8*)(smem + LDS_QT + col * 2048 +
                                  (kb ^ ((col & 7) << 4)));
          } else {
            av = *(const bf16x8*)(smem + LDS_Z16);
          }
          bf16x8 bv = *(const bf16x8*)(smem + LDS_WFRAG + tile * 32768 +
                                       kc * 1024 + lane * 16);
          acc4 = __builtin_amdgcn_mfma_f32_16x16x32_bf16(av, bv, acc4, 0, 0, 0);
        }
        if (lane < 32) {
          const int r0 = (lane >> 4) * 4;
#pragma unroll
          for (int e = 0; e < 4; ++e)
            Lb[(r0 + e) * 64 + tile * 16 + col] = acc4[e];
        }
      } else if (w == 4 && bid == 0) {
        // -- exact blank logit (seeds Res; payload 0 => v = VBLANK) --
        const int kb0 = lane * 16;
#pragma unroll
        for (int r = 0; r < 8; ++r) {
          float sum = 0.f;
#pragma unroll
          for (int e = 0; e < 16; e += 4) {
            f32x4 wv = *(const f32x4*)(WoutT + (size_t)VBLANK * HD + kb0 + e);
            f32x4 q2 = ald4(qg + r * HD + kb0 + e);
            sum += wv[0] * q2[0] + wv[1] * q2[1] + wv[2] * q2[2] + wv[3] * q2[3];
          }
          sum += __shfl_xor(sum, 1);
          sum += __shfl_xor(sum, 2);
          sum += __shfl_xor(sum, 4);
          sum += __shfl_xor(sum, 8);
          sum += __shfl_xor(sum, 16);
          sum += __shfl_xor(sum, 32);
          if (lane == 0) {
            float L = sum + bout[VBLANK];
            atomicMax(&Res[r], ((unsigned long long)mono32(L)) << 32);
          }
        }
      }
      __syncthreads();
      // -- block-local certified threshold, candidate list --
      {
        const float* bnd = (const float*)(smem + LDS_BND);
        const float Ld = Lb[w * 64 + lane];
        float m = Ld - bnd[lane];
        m = fmaxf(m, __shfl_xor(m, 1));
        m = fmaxf(m, __shfl_xor(m, 2));
        m = fmaxf(m, __shfl_xor(m, 4));
        m = fmaxf(m, __shfl_xor(m, 8));
        m = fmaxf(m, __shfl_xor(m, 16));
        m = fmaxf(m, __shfl_xor(m, 32));
        if (Ld + bnd[lane] >= m) {
          unsigned pos = atomicAdd(cnt, 1u);
          list[pos] = ((unsigned)w << 16) | (unsigned)(bid * 64 + lane);
        }
      }
      __syncthreads();
      // -- exact fp32 rescore of candidates (WoutT cached RO, qg via L3) --
      const unsigned nc = *cnt;
      for (unsigned ci = (unsigned)w; ci < nc; ci += 8) {
        const unsigned ent = list[ci];
        const int rr2 = (int)(ent >> 16), v = (int)(ent & 0xFFFFu);
        const int kb0 = lane * 16;
        float sum = 0.f;
#pragma unroll
        for (int e = 0; e < 16; e += 4) {
          f32x4 q2 = ald4(qg + rr2 * HD + kb0 + e);
          f32x4 wv = *(const f32x4*)(WoutT + (size_t)v * HD + kb0 + e);
          sum += q2[0] * wv[0] + q2[1] * wv[1] + q2[2] * wv[2] + q2[3] * wv[3];
        }
        sum += __shfl_xor(sum, 1);
        sum += __shfl_xor(sum, 2);
        sum += __shfl_xor(sum, 4);
        sum += __shfl_xor(sum, 8);
        sum += __shfl_xor(sum, 16);
        sum += __shfl_xor(sum, 32);
        if (lane == 0) {
          float L = sum + bout[v];
          atomicMax(&Res[rr2], (((unsigned long long)mono32(L)) << 32) |
                                   (unsigned long long)(unsigned)(VBLANK - v));
        }
      }
    }
    gridbar(barc, barg, ++bep, bflag);
  }  // s loop

  // ================= epilogue =================
  {
    if (tid < 8) {
      unsigned long long rv = __hip_atomic_load(&Res[tid], AT_RLX, SC_AGT);
      ((int*)(smem + LDS_SYM))[tid] =
          VBLANK - (int)(unsigned)(rv & 0xFFFFFFFFull);
    }
    __syncthreads();
    int sym[8];
#pragma unroll
    for (int r = 0; r < 8; ++r) sym[r] = ((const int*)(smem + LDS_SYM))[r];
    if (bid == 0 && tid < 8) {
      int lab = ((actmask >> tid) & 1) ? sym[tid] : VBLANK;
      out[((size_t)tid * TMAX + (Tloop - 1)) * 4 + 3] = (float)lab;
    }
    unsigned advf = 0;
#pragma unroll
    for (int r = 0; r < 8; ++r)
      if (((actmask >> r) & 1) && sym[r] != VBLANK) advf |= 1u << r;
    if (tid < 32) {
      const int r = tid >> 2, j = tid & 3, col = 4 * bid + j;
      const bool ad = (advf >> r) & 1;
      float hold = __hip_atomic_load(&hA[r * HD + col], AT_RLX, SC_AGT);
      out[6400 + (size_t)r * HD + col] = ad ? h2l : hold;
      out[6400 + 8192 + (size_t)r * HD + col] = ad ? c2l : cst;
    }
    if (bid == 0 && Tloop < TMAX) {
      const int per = (TMAX - Tloop) * 4;
      const int ntail = 8 * per;
      for (int idx = tid; idx < ntail; idx += NTHR) {
        int r = idx / per, rem = idx % per;
        int tt = Tloop + (rem >> 2), uu = rem & 3;
        out[((size_t)r * TMAX + tt) * 4 + uu] = (float)VBLANK;
      }
    }
  }
}

// ============================================================================
extern "C" void kernel_launch(void* const* d_in, const int* in_sizes, int n_in,
                              void* d_out, int out_size, void* d_ws,
                              size_t ws_size, hipStream_t stream) {
  const float* enc = (const float*)d_in[0];   // (8,1024,200)
  const int* lens = (const int*)d_in[1];      // (8,)
  const float* emb = (const float*)d_in[2];   // (16385,1024)
  const float* Wx = (const float*)d_in[3];    // (1024,4096)
  const float* Wh = (const float*)d_in[4];    // (1024,4096)
  const float* b = (const float*)d_in[5];     // (4096,)
  const float* Wenc = (const float*)d_in[6];  // (1024,1024)
  const float* Wpred = (const float*)d_in[7]; // (1024,1024)
  const float* bj = (const float*)d_in[8];    // (1024,)
  const float* Wout = (const float*)d_in[9];  // (1024,16385)
  const float* bout = (const float*)d_in[10]; // (16385,)
  float* out = (float*)d_out;                 // labels(6400)|h(8192)|c(8192)

  float* ws = (float*)d_ws;                   // ~118 MB
  float* encT = ws;                           // 8*200*1024      = 1638400
  float* E = encT + 1638400;                  // 200*8*1024      = 1638400
  float* WxT = E + 1638400;                   // 4096*1024       = 4194304
  float* WhT = WxT + 4194304;                 // 4096*1024       = 4194304
  float* WpT = WhT + 4194304;                 // 1024*1024       = 1048576
  float* WoutT = WpT + 1048576;               // 16385*1024      = 16778240
  float* qg = WoutT + 16778240;               // 8192
  unsigned* qgb = (unsigned*)(qg + 8192);     // 1024 u32 (bf16 q pairs)
  float* hA = (float*)(qgb + 1024);           // 8192
  float* hB0 = hA + 8192;                     // 8192
  float* hB1 = hB0 + 8192;                    // 8192
  unsigned long long* Res = (unsigned long long*)(hB1 + 8192);  // 8 u64
  unsigned* barc = (unsigned*)(Res + 8) + 32; // own cacheline
  unsigned* barg = barc + 32;                 // own cacheline

  hipFuncSetAttribute(reinterpret_cast<const void*>(decode_kernel),
                      hipFuncAttributeMaxDynamicSharedMemorySize, LDS_TOTAL);

  hipMemsetAsync(hA, 0, 8192 * sizeof(float), stream);  // h0 = 0
  hipMemsetAsync(Res, 0, 512, stream);                  // Res + barc + barg

  trk<<<dim3(128, 32, 1), dim3(32, 8), 0, stream>>>(Wx, WxT, 1024, 4096);
  trk<<<dim3(128, 32, 1), dim3(32, 8), 0, stream>>>(Wh, WhT, 1024, 4096);
  trk<<<dim3(32, 32, 1), dim3(32, 8), 0, stream>>>(Wpred, WpT, 1024, 1024);
  trk<<<dim3(7, 32, 8), dim3(32, 8), 0, stream>>>(enc, encT, 1024, 200);
  trk<<<dim3(513, 32, 1), dim3(32, 8), 0, stream>>>(Wout, WoutT, 1024, NVOC);
  egemm_kernel<<<dim3(50, 4), 512, 0, stream>>>(encT, Wenc, E);

  void* params[] = {(void*)&lens, (void*)&emb,  (void*)&b,   (void*)&bj,
                    (void*)&bout, (void*)&WxT,  (void*)&WhT, (void*)&WpT,
                    (void*)&WoutT,(void*)&E,    (void*)&qg,  (void*)&qgb,
                    (void*)&hA,   (void*)&hB0,  (void*)&hB1, (void*)&Res,
                    (void*)&barc, (void*)&barg, (void*)&out};
  hipLaunchCooperativeKernel(reinterpret_cast<const void*>(decode_kernel),
                             dim3(NBLK), dim3(NTHR), params, LDS_TOTAL, stream);
}